// Round 1
// baseline (490.194 us; speedup 1.0000x reference)
//
#include <hip/hip_runtime.h>
#include <hip/hip_bf16.h>

// Deformable conv v1: pad/transpose -> NHWC bf16; VALU offset conv;
// deformed-im2col + MFMA 16x16x32 bf16 main conv.
//
// ws layout (bytes):
//   [0)            xpT   bf16 [8][130][130][64]   = 17,305,600
//   [17305600)     offsets f32 [8*128*128][18]    =  9,437,184
//   [26742784)     Bpack bf16 frags [18][4][64][8]=     73,728
//   [26816512)     wOffT f32 [9][18][64]          =     41,472

#define PH   130
#define CIN  64
#define COUT 64
#define APITCH 584   // 576 + 8 bf16 pad: breaks 1152B-stride bank conflict on ds_read_b128

typedef __attribute__((ext_vector_type(8))) __bf16 bf16x8;
typedef __attribute__((ext_vector_type(4))) float  f32x4;

__device__ __forceinline__ short f2bf(float f) {
  __hip_bfloat16 h = __float2bfloat16(f);
  return __builtin_bit_cast(short, h);
}
__device__ __forceinline__ float bf2f(__hip_bfloat16 h) { return __bfloat162float(h); }

// ---------------- K1: pad + NCHW->NHWC transpose, fp32 -> bf16 -------------
__global__ __launch_bounds__(256) void k_pad_transpose(
    const float* __restrict__ x, __hip_bfloat16* __restrict__ xpT) {
  __shared__ __hip_bfloat16 tile[128 * 64];  // [w][c], c XOR-swizzled by (w>>2)&7
  int bid = blockIdx.x;            // 8*130 blocks: one padded row each
  int n = bid / PH;
  int y = bid % PH;
  int tid = threadIdx.x;
  bool interior = (y >= 1 && y <= 128);
  if (interior) {
    for (int i = tid; i < 2048; i += 256) {       // 64 ch x 32 float4
      int c  = i >> 5;
      int w4 = (i & 31) << 2;
      float4 v = *(const float4*)(x + (((size_t)(n * 64 + c) * 128) + (y - 1)) * 128 + w4);
      int sw = (i & 7) << 3;                       // ((w>>2)&7)<<3, same for 4 lanes
      tile[(w4 + 0) * 64 + (c ^ sw)] = __float2bfloat16(v.x);
      tile[(w4 + 1) * 64 + (c ^ sw)] = __float2bfloat16(v.y);
      tile[(w4 + 2) * 64 + (c ^ sw)] = __float2bfloat16(v.z);
      tile[(w4 + 3) * 64 + (c ^ sw)] = __float2bfloat16(v.w);
    }
  }
  __syncthreads();
  __hip_bfloat16* dst = xpT + (size_t)(n * PH + y) * PH * CIN;
  bool zrow = (y == 0 || y == PH - 1);
  for (int i = tid; i < 1040; i += 256) {          // 130 px * 64 ch / 8
    int px = i >> 3;
    int c0 = (i & 7) << 3;
    uint4 v;
    if (zrow || px == 0 || px == PH - 1) {
      v = make_uint4(0u, 0u, 0u, 0u);
    } else {
      int pxi = px - 1;
      int c0s = c0 ^ (((pxi >> 2) & 7) << 3);
      v = *(const uint4*)&tile[pxi * 64 + c0s];
    }
    *(uint4*)(dst + (size_t)i * 8) = v;
  }
}

// ---------------- Kprep: pack weights ---------------------------------------
// Bpack[kk][nt][lane][i] = bf16( w_conv[co=nt*16+(lane&15)][ci][tap] ),
//   k = kk*32 + 8*(lane>>4) + i, tap = k/64, ci = k%64  (A k-order = tap*64+ci)
// wOffT[(tap*18+co)*64+ci] = w_off[co][ci][tap]
__global__ __launch_bounds__(256) void k_prep(
    const float* __restrict__ w_off, const float* __restrict__ w_conv,
    short* __restrict__ Bpack, float* __restrict__ wOffT) {
  int t = blockIdx.x * 256 + threadIdx.x;
  if (t < 18 * 4 * 64) {
    int lane = t & 63;
    int nt   = (t >> 6) & 3;
    int kk   = t >> 8;
    int co   = nt * 16 + (lane & 15);
    int kbase = kk * 32 + ((lane >> 4) << 3);
    short v[8];
#pragma unroll
    for (int i = 0; i < 8; ++i) {
      int k = kbase + i;
      int tap = k >> 6;
      int ci  = k & 63;
      v[i] = f2bf(w_conv[(size_t)(co * 64 + ci) * 9 + tap]);
    }
    *(uint4*)(Bpack + (size_t)t * 8) = *(const uint4*)v;
  }
  int u = t - 18 * 4 * 64;
  if (u >= 0 && u < 9 * 18 * 64) {
    int ci = u & 63;
    int r  = u >> 6;
    int co = r % 18;
    int tap = r / 18;
    wOffT[u] = w_off[(size_t)(co * 64 + ci) * 9 + tap];
  }
}

// ---------------- K2: offset conv (18 channels) -----------------------------
// wave-per-pixel, lane = cin; shuffle-reduce the 18 partials.
__global__ __launch_bounds__(256) void k_offset_conv(
    const __hip_bfloat16* __restrict__ xpT, const float* __restrict__ wOffT,
    const float* __restrict__ b_off, float* __restrict__ offsets) {
  __shared__ float wl[9 * 18 * 64];  // 41.5 KB
  int tid = threadIdx.x;
  for (int i = tid; i < 9 * 18 * 64; i += 256) wl[i] = wOffT[i];
  __syncthreads();
  int n = blockIdx.x >> 7;          // 8*128 blocks: one output row each
  int h = blockIdx.x & 127;
  int wave = tid >> 6, lane = tid & 63;
  const __hip_bfloat16* xb = xpT + (size_t)n * PH * PH * CIN;
  for (int wp = wave; wp < 128; wp += 4) {
    float p[18];
#pragma unroll
    for (int co = 0; co < 18; ++co) p[co] = 0.f;
#pragma unroll
    for (int tap = 0; tap < 9; ++tap) {
      int ky = tap / 3, kx = tap - 3 * (tap / 3);
      float v = bf2f(xb[((size_t)(h + ky) * PH + (wp + kx)) * CIN + lane]);
      const float* wrow = &wl[tap * 18 * 64 + lane];
#pragma unroll
      for (int co = 0; co < 18; ++co) p[co] += v * wrow[co * 64];
    }
    float myval = 0.f;
#pragma unroll
    for (int co = 0; co < 18; ++co) {
      float r = p[co];
      r += __shfl_xor(r, 32);
      r += __shfl_xor(r, 16);
      r += __shfl_xor(r, 8);
      r += __shfl_xor(r, 4);
      r += __shfl_xor(r, 2);
      r += __shfl_xor(r, 1);
      if (lane == co) myval = r;
    }
    if (lane < 18) {
      size_t pix = (size_t)((n * 128 + h) * 128 + wp);
      offsets[pix * 18 + lane] = myval + b_off[lane];
    }
  }
}

// ---------------- K3: deformed im2col + MFMA main conv ----------------------
// block = 64 pixels (half an output row) x 64 cout; 4 waves.
__global__ __launch_bounds__(256, 2) void k_main(
    const __hip_bfloat16* __restrict__ xpT, const float* __restrict__ offsets,
    const short* __restrict__ Bpack, const float* __restrict__ b_conv,
    float* __restrict__ out) {
  __shared__ __attribute__((aligned(16))) __hip_bfloat16 Atile[64 * APITCH];  // 74,752 B
  int bid = blockIdx.x;             // 8*128*2
  int wh  = bid & 1;
  int h   = (bid >> 1) & 127;
  int n   = bid >> 8;
  int w0  = wh << 6;
  int tid = threadIdx.x, wave = tid >> 6, lane = tid & 63;
  size_t pixbase = (size_t)((n * 128 + h) * 128 + w0);
  const __hip_bfloat16* xb = xpT + (size_t)n * PH * PH * CIN;

  // ---- build deformed im2col A-tile: 576 (pixel,tap) pairs, lane = channel
  for (int pp = wave; pp < 576; pp += 4) {
    int pixel = pp / 9;
    int tap   = pp - 9 * pixel;
    int ky = tap / 3, kx = tap - 3 * (tap / 3);
    const float* offp = offsets + (pixbase + pixel) * 18;
    float cx = offp[tap]     + (float)(w0 + pixel + kx);  // (1+w)+(kx-1)
    float cy = offp[9 + tap] + (float)(h + ky);
    cx = fminf(fmaxf(cx, 0.f), (float)(PH - 1));
    cy = fminf(fmaxf(cy, 0.f), (float)(PH - 1));
    float x0f = floorf(cx), y0f = floorf(cy);
    float wx = cx - x0f, wy = cy - y0f;
    int x0 = (int)x0f, y0 = (int)y0f;
    int x1 = min(x0 + 1, PH - 1), y1 = min(y0 + 1, PH - 1);
    float g00 = bf2f(xb[((size_t)y0 * PH + x0) * CIN + lane]);
    float g01 = bf2f(xb[((size_t)y0 * PH + x1) * CIN + lane]);
    float g10 = bf2f(xb[((size_t)y1 * PH + x0) * CIN + lane]);
    float g11 = bf2f(xb[((size_t)y1 * PH + x1) * CIN + lane]);
    float s0 = g00 + wx * (g01 - g00);
    float s1 = g10 + wx * (g11 - g10);
    float s  = s0 + wy * (s1 - s0);
    Atile[pixel * APITCH + tap * 64 + lane] = __float2bfloat16(s);
  }
  __syncthreads();

  // ---- MFMA: M=16/wave, N=64 (4 tiles), K=576 (18 steps)
  f32x4 acc0 = {0.f, 0.f, 0.f, 0.f}, acc1 = acc0, acc2 = acc0, acc3 = acc0;
  int arow = wave * 16 + (lane & 15);
  int kofs = (lane >> 4) << 3;
  const bf16x8* Bp = (const bf16x8*)Bpack;
#pragma unroll
  for (int kk = 0; kk < 18; ++kk) {
    bf16x8 a  = *(const bf16x8*)&Atile[arow * APITCH + kk * 32 + kofs];
    bf16x8 b0 = Bp[(kk * 4 + 0) * 64 + lane];
    bf16x8 b1 = Bp[(kk * 4 + 1) * 64 + lane];
    bf16x8 b2 = Bp[(kk * 4 + 2) * 64 + lane];
    bf16x8 b3 = Bp[(kk * 4 + 3) * 64 + lane];
    acc0 = __builtin_amdgcn_mfma_f32_16x16x32_bf16(a, b0, acc0, 0, 0, 0);
    acc1 = __builtin_amdgcn_mfma_f32_16x16x32_bf16(a, b1, acc1, 0, 0, 0);
    acc2 = __builtin_amdgcn_mfma_f32_16x16x32_bf16(a, b2, acc2, 0, 0, 0);
    acc3 = __builtin_amdgcn_mfma_f32_16x16x32_bf16(a, b3, acc3, 0, 0, 0);
  }
  __syncthreads();

  // ---- epilogue: LDS transpose (pitch 68 breaks conflicts), coalesced store
  float* olds = (float*)Atile;      // 64*68*4 = 17,408 B, reuses Atile
  int prow0 = wave * 16 + ((lane >> 4) << 2);
  int c0 = lane & 15;
#pragma unroll
  for (int r = 0; r < 4; ++r) {
    olds[(prow0 + r) * 68 + c0     ] = acc0[r];
    olds[(prow0 + r) * 68 + c0 + 16] = acc1[r];
    olds[(prow0 + r) * 68 + c0 + 32] = acc2[r];
    olds[(prow0 + r) * 68 + c0 + 48] = acc3[r];
  }
  __syncthreads();
  float* ob = out + (size_t)n * COUT * 128 * 128 + (size_t)h * 128 + w0;
  for (int i = tid; i < 4096; i += 256) {
    int co = i >> 6, p = i & 63;
    ob[(size_t)co * 16384 + p] = olds[p * 68 + co] + b_conv[co];
  }
}

// ---------------------------------------------------------------------------
extern "C" void kernel_launch(void* const* d_in, const int* in_sizes, int n_in,
                              void* d_out, int out_size, void* d_ws, size_t ws_size,
                              hipStream_t stream) {
  const float* x      = (const float*)d_in[0];
  const float* w_off  = (const float*)d_in[1];
  const float* b_off  = (const float*)d_in[2];
  const float* w_conv = (const float*)d_in[3];
  const float* b_conv = (const float*)d_in[4];
  float* out = (float*)d_out;

  char* ws = (char*)d_ws;
  __hip_bfloat16* xpT = (__hip_bfloat16*)ws;                       // 17,305,600 B
  float* offsets = (float*)(ws + 17305600);                        //  9,437,184 B
  short* Bpack   = (short*)(ws + 17305600 + 9437184);              //     73,728 B
  float* wOffT   = (float*)(ws + 17305600 + 9437184 + 73728);      //     41,472 B

  k_pad_transpose<<<dim3(8 * PH), dim3(256), 0, stream>>>(x, xpT);
  k_prep<<<dim3(59), dim3(256), 0, stream>>>(w_off, w_conv, Bpack, wOffT);
  k_offset_conv<<<dim3(8 * 128), dim3(256), 0, stream>>>(xpT, wOffT, b_off, offsets);
  k_main<<<dim3(2048), dim3(256), 0, stream>>>(xpT, offsets, Bpack, b_conv, out);
}

// Round 4
// 197.918 us; speedup vs baseline: 2.4768x; 2.4768x over previous
//
#include <hip/hip_runtime.h>
#include <hip/hip_bf16.h>

// Deformable conv v2: fully fused offset-conv + deformed-sampling + main conv.
//   k_pad_transpose: NCHW fp32 -> padded NHWC bf16 (xpT)
//   k_prep:          pack w_conv (4 n-tiles) and w_off (2 n-tiles, co>=18 -> 0)
//                    into MFMA B-fragment order
//   k_fused:         per block = 64 output pixels:
//     P1: offset conv via MFMA (regular im2col A-frags in registers)
//     P2: sampling metadata (base addr, wx, wy, dx|dy) once per (pixel,tap)
//     P3: main conv, deformed A-frags built in registers (gather+lerp), MFMA
//     P4: LDS-transpose epilogue, coalesced NCHW store
//
// ws layout (bytes):
//   [0)          xpT      bf16 [8][130][130][64] = 17,305,600
//   [17305600)   Bpack    bf16 [18][4][64][8]    =     73,728
//   [17379328)   wOffPack bf16 [18][2][64][8]    =     36,864

#define PH   130
#define CIN  64
#define COUT 64

typedef __attribute__((ext_vector_type(8))) __bf16 bf16x8;
typedef __attribute__((ext_vector_type(4))) float  f32x4;

__device__ __forceinline__ short f2bf(float f) {
  return __builtin_bit_cast(short, __float2bfloat16(f));
}
__device__ __forceinline__ float blo(unsigned u) {
  return __builtin_bit_cast(float, u << 16);
}
__device__ __forceinline__ float bhi(unsigned u) {
  return __builtin_bit_cast(float, u & 0xffff0000u);
}
__device__ __forceinline__ unsigned packbf(float a, float b) {
  unsigned lo16 = (unsigned short)__builtin_bit_cast(unsigned short, __float2bfloat16(a));
  unsigned hi16 = (unsigned short)__builtin_bit_cast(unsigned short, __float2bfloat16(b));
  return lo16 | (hi16 << 16);
}

// ---------------- K1: pad + NCHW->NHWC transpose, fp32 -> bf16 -------------
__global__ __launch_bounds__(256) void k_pad_transpose(
    const float* __restrict__ x, __hip_bfloat16* __restrict__ xpT) {
  __shared__ __hip_bfloat16 tile[128 * 64];  // [w][c], c XOR-swizzled by (w>>2)&7
  int bid = blockIdx.x;            // 8*130 blocks: one padded row each
  int n = bid / PH;
  int y = bid % PH;
  int tid = threadIdx.x;
  bool interior = (y >= 1 && y <= 128);
  if (interior) {
    for (int i = tid; i < 2048; i += 256) {       // 64 ch x 32 float4
      int c  = i >> 5;
      int w4 = (i & 31) << 2;
      float4 v = *(const float4*)(x + (((size_t)(n * 64 + c) * 128) + (y - 1)) * 128 + w4);
      int sw = (i & 7) << 3;
      tile[(w4 + 0) * 64 + (c ^ sw)] = __float2bfloat16(v.x);
      tile[(w4 + 1) * 64 + (c ^ sw)] = __float2bfloat16(v.y);
      tile[(w4 + 2) * 64 + (c ^ sw)] = __float2bfloat16(v.z);
      tile[(w4 + 3) * 64 + (c ^ sw)] = __float2bfloat16(v.w);
    }
  }
  __syncthreads();
  __hip_bfloat16* dst = xpT + (size_t)(n * PH + y) * PH * CIN;
  bool zrow = (y == 0 || y == PH - 1);
  for (int i = tid; i < 1040; i += 256) {          // 130 px * 64 ch / 8
    int px = i >> 3;
    int c0 = (i & 7) << 3;
    uint4 v;
    if (zrow || px == 0 || px == PH - 1) {
      v = make_uint4(0u, 0u, 0u, 0u);
    } else {
      int pxi = px - 1;
      int c0s = c0 ^ (((pxi >> 2) & 7) << 3);
      v = *(const uint4*)&tile[pxi * 64 + c0s];
    }
    *(uint4*)(dst + (size_t)i * 8) = v;
  }
}

// ---------------- Kprep: pack both weight tensors into B-frag order ---------
// frag element i of lane l, k-step kk:  k = kk*32 + (l>>4)*8 + i,
//   tap = k/64, ci = k%64, co = nt*16 + (l&15).
__global__ __launch_bounds__(256) void k_prep(
    const float* __restrict__ w_off, const float* __restrict__ w_conv,
    short* __restrict__ Bpack, short* __restrict__ wOffPack) {
  int t = blockIdx.x * 256 + threadIdx.x;
  if (t < 18 * 4 * 64) {
    int lane = t & 63;
    int nt   = (t >> 6) & 3;
    int kk   = t >> 8;
    int co   = nt * 16 + (lane & 15);
    int kbase = kk * 32 + ((lane >> 4) << 3);
    short v[8];
#pragma unroll
    for (int i = 0; i < 8; ++i) {
      int k = kbase + i;
      v[i] = f2bf(w_conv[(size_t)(co * 64 + (k & 63)) * 9 + (k >> 6)]);
    }
    *(uint4*)(Bpack + (size_t)t * 8) = *(const uint4*)v;
  }
  int u = t - 18 * 4 * 64;
  if (u >= 0 && u < 18 * 2 * 64) {
    int lane = u & 63;
    int nt   = (u >> 6) & 1;
    int kk   = u >> 7;
    int co   = nt * 16 + (lane & 15);
    int kbase = kk * 32 + ((lane >> 4) << 3);
    short v[8];
#pragma unroll
    for (int i = 0; i < 8; ++i) {
      int k = kbase + i;
      v[i] = (co < 18) ? f2bf(w_off[(size_t)(co * 64 + (k & 63)) * 9 + (k >> 6)]) : (short)0;
    }
    *(uint4*)(wOffPack + (size_t)u * 8) = *(const uint4*)v;
  }
}

// ---------------- K2: fused offset conv + deform sample + main conv ---------
__global__ __launch_bounds__(256, 4) void k_fused(
    const __hip_bfloat16* __restrict__ xpT, const short* __restrict__ Bpack,
    const short* __restrict__ wOffPack, const float* __restrict__ b_off,
    const float* __restrict__ b_conv, float* __restrict__ out) {
  __shared__ __attribute__((aligned(16))) char shraw[17408];
  float* offsLds = (float*)shraw;            // [64 pix][20]  (co 0..17 used)
  int4*  metaLds = (int4*)(shraw + 5120);    // [64 pix][9 taps]
  float* olds    = (float*)shraw;            // [64 pix][68]  (epilogue reuse)

  int bid = blockIdx.x;                      // 8*128*2
  int wh  = bid & 1;
  int h   = (bid >> 1) & 127;
  int n   = bid >> 8;
  int w0  = wh << 6;
  int tid = threadIdx.x, wv = tid >> 6, lane = tid & 63;
  int p = lane & 15, oct = lane >> 4;
  const char* xbB = (const char*)(xpT + (size_t)n * PH * PH * CIN);

  // ---- P1: offset conv. M=16 pixels/wave, N=32 (co<18 live), K=576.
  {
    f32x4 ao0 = {0.f, 0.f, 0.f, 0.f}, ao1 = ao0;
    int wpix = w0 + wv * 16 + p;
    const bf16x8* Wo = (const bf16x8*)wOffPack;
#pragma unroll
    for (int kk = 0; kk < 18; ++kk) {
      int tap = kk >> 1;
      int ky = tap / 3, kx = tap - (tap / 3) * 3;
      int ci0 = ((kk & 1) << 5) + (oct << 3);
      int off = (((h + ky) * PH + (wpix + kx)) * CIN + ci0) * 2;
      bf16x8 a  = *(const bf16x8*)(xbB + off);
      bf16x8 b0 = Wo[(kk * 2 + 0) * 64 + lane];
      bf16x8 b1 = Wo[(kk * 2 + 1) * 64 + lane];
      ao0 = __builtin_amdgcn_mfma_f32_16x16x32_bf16(a, b0, ao0, 0, 0, 0);
      ao1 = __builtin_amdgcn_mfma_f32_16x16x32_bf16(a, b1, ao1, 0, 0, 0);
    }
    // C/D: col = lane&15 (=co), row = oct*4+r (=pixel within wave's 16)
    int co = lane & 15;
    float bo0 = b_off[co];
#pragma unroll
    for (int r = 0; r < 4; ++r)
      offsLds[(wv * 16 + oct * 4 + r) * 20 + co] = ao0[r] + bo0;
    if (co < 2) {
      float bo1 = b_off[16 + co];
#pragma unroll
      for (int r = 0; r < 4; ++r)
        offsLds[(wv * 16 + oct * 4 + r) * 20 + 16 + co] = ao1[r] + bo1;
    }
  }
  __syncthreads();

  // ---- P2: sampling metadata, one (pixel,tap) per thread.
  for (int t = tid; t < 576; t += 256) {
    int pix = t / 9, tap = t - pix * 9;
    int ky = tap / 3, kx = tap - (tap / 3) * 3;
    float cx = offsLds[pix * 20 + tap]     + (float)(w0 + pix + kx);
    float cy = offsLds[pix * 20 + 9 + tap] + (float)(h + ky);
    cx = fminf(fmaxf(cx, 0.f), 129.f);
    cy = fminf(fmaxf(cy, 0.f), 129.f);
    float x0f = floorf(cx), y0f = floorf(cy);
    int x0 = (int)x0f, y0 = (int)y0f;
    float wx = cx - x0f, wy = cy - y0f;
    int baseB = (y0 * PH + x0) << 7;                    // *128 bytes (64ch*2B)
    int dxdy = ((x0 < PH - 1) ? 128 : 0) | (((y0 < PH - 1) ? PH * 128 : 0) << 16);
    metaLds[t] = make_int4(baseB, __builtin_bit_cast(int, wx),
                           __builtin_bit_cast(int, wy), dxdy);
  }
  __syncthreads();

  // ---- P3: main conv, deformed A-frags in registers.
  f32x4 acc0 = {0.f, 0.f, 0.f, 0.f}, acc1 = acc0, acc2 = acc0, acc3 = acc0;
  const bf16x8* Bp = (const bf16x8*)Bpack;
  int mbase = (wv * 16 + p) * 9;
#pragma unroll
  for (int tap = 0; tap < 9; ++tap) {
    int4 mt = metaLds[mbase + tap];
    float wx = __builtin_bit_cast(float, mt.y);
    float wy = __builtin_bit_cast(float, mt.z);
    int dx = mt.w & 0xffff;
    int dy = (mt.w >> 16) & 0xffff;
    float w11 = wx * wy;
    float w01 = wx - w11;          // wx*(1-wy)
    float w10 = wy - w11;          // (1-wx)*wy
    float w00 = 1.f - wx - w10;    // (1-wx)*(1-wy)
    const char* pb = xbB + (mt.x + (oct << 4));
#pragma unroll
    for (int half = 0; half < 2; ++half) {
      const char* pc = pb + (half << 6);
      uint4 q00 = *(const uint4*)(pc);
      uint4 q01 = *(const uint4*)(pc + dx);
      uint4 q10 = *(const uint4*)(pc + dy);
      uint4 q11 = *(const uint4*)(pc + dx + dy);
      unsigned av[4];
#pragma unroll
      for (int j = 0; j < 4; ++j) {
        unsigned u00 = ((const unsigned*)&q00)[j];
        unsigned u01 = ((const unsigned*)&q01)[j];
        unsigned u10 = ((const unsigned*)&q10)[j];
        unsigned u11 = ((const unsigned*)&q11)[j];
        float sl = blo(u00) * w00 + blo(u01) * w01 + blo(u10) * w10 + blo(u11) * w11;
        float sh = bhi(u00) * w00 + bhi(u01) * w01 + bhi(u10) * w10 + bhi(u11) * w11;
        av[j] = packbf(sl, sh);
      }
      bf16x8 a = __builtin_bit_cast(bf16x8, *(uint4*)av);
      int kk = tap * 2 + half;
      bf16x8 b0 = Bp[(kk * 4 + 0) * 64 + lane];
      bf16x8 b1 = Bp[(kk * 4 + 1) * 64 + lane];
      bf16x8 b2 = Bp[(kk * 4 + 2) * 64 + lane];
      bf16x8 b3 = Bp[(kk * 4 + 3) * 64 + lane];
      acc0 = __builtin_amdgcn_mfma_f32_16x16x32_bf16(a, b0, acc0, 0, 0, 0);
      acc1 = __builtin_amdgcn_mfma_f32_16x16x32_bf16(a, b1, acc1, 0, 0, 0);
      acc2 = __builtin_amdgcn_mfma_f32_16x16x32_bf16(a, b2, acc2, 0, 0, 0);
      acc3 = __builtin_amdgcn_mfma_f32_16x16x32_bf16(a, b3, acc3, 0, 0, 0);
    }
  }
  __syncthreads();

  // ---- P4: epilogue via LDS transpose (pitch 68), coalesced NCHW store.
  int prow0 = wv * 16 + (oct << 2);
#pragma unroll
  for (int r = 0; r < 4; ++r) {
    olds[(prow0 + r) * 68 + p     ] = acc0[r];
    olds[(prow0 + r) * 68 + p + 16] = acc1[r];
    olds[(prow0 + r) * 68 + p + 32] = acc2[r];
    olds[(prow0 + r) * 68 + p + 48] = acc3[r];
  }
  __syncthreads();
  float* ob = out + (size_t)n * COUT * 16384 + (size_t)h * 128 + w0;
  for (int i = tid; i < 4096; i += 256) {
    int co = i >> 6, px = i & 63;
    ob[(size_t)co * 16384 + px] = olds[px * 68 + co] + b_conv[co];
  }
}

// ---------------------------------------------------------------------------
extern "C" void kernel_launch(void* const* d_in, const int* in_sizes, int n_in,
                              void* d_out, int out_size, void* d_ws, size_t ws_size,
                              hipStream_t stream) {
  const float* x      = (const float*)d_in[0];
  const float* w_off  = (const float*)d_in[1];
  const float* b_off  = (const float*)d_in[2];
  const float* w_conv = (const float*)d_in[3];
  const float* b_conv = (const float*)d_in[4];
  float* out = (float*)d_out;

  char* ws = (char*)d_ws;
  __hip_bfloat16* xpT = (__hip_bfloat16*)ws;             // 17,305,600 B
  short* Bpack    = (short*)(ws + 17305600);             //     73,728 B
  short* wOffPack = (short*)(ws + 17305600 + 73728);     //     36,864 B

  k_pad_transpose<<<dim3(8 * PH), dim3(256), 0, stream>>>(x, xpT);
  k_prep<<<dim3(27), dim3(256), 0, stream>>>(w_off, w_conv, Bpack, wOffPack);
  k_fused<<<dim3(2048), dim3(256), 0, stream>>>(xpT, Bpack, wOffPack, b_off, b_conv, out);
}